// Round 10
// baseline (274.980 us; speedup 1.0000x reference)
//
#include <hip/hip_runtime.h>
#include <stdint.h>

#define K_IN  4096
#define N_OUT 4096
#define M_TOK 4096

#define MODE_F16  0
#define MODE_BF16 1
#define MODE_F32  2

typedef __attribute__((ext_vector_type(8))) short    bf16x8;
typedef _Float16 f16x8 __attribute__((ext_vector_type(8)));
typedef _Float16 h2    __attribute__((ext_vector_type(2)));
typedef __attribute__((ext_vector_type(4))) float    f32x4;

static __device__ __forceinline__ float bflo(uint32_t u) {
    union { uint32_t u; float f; } c; c.u = u << 16; return c.f;
}
static __device__ __forceinline__ float bfhi(uint32_t u) {
    union { uint32_t u; float f; } c; c.u = u & 0xFFFF0000u; return c.f;
}
static __device__ __forceinline__ uint16_t f2b(float f) {
    union { float f; uint32_t u; } c; c.f = f;
    uint32_t r = c.u + 0x7FFFu + ((c.u >> 16) & 1u);   // RNE
    return (uint16_t)(r >> 16);
}
static __device__ __forceinline__ uint16_t f2h(float f) {
    union { uint16_t u; _Float16 h; } c; c.h = (_Float16)f; return c.u;
}
static __device__ __forceinline__ uint32_t pk(float a, float b) {
    return (uint32_t)f2b(a) | ((uint32_t)f2b(b) << 16);
}
static __device__ __forceinline__ uint32_t fma_h2(uint32_t g, uint32_t r, h2 s) {
    union { uint32_t u; h2 h; } G, R, W;
    G.u = g; R.u = r;
    W.h = G.h + s * R.h;
    return W.u;
}
static __device__ __forceinline__ uint32_t fma_b2(uint32_t g, uint32_t r, float s) {
    return pk(bflo(g) + s * bflo(r), bfhi(g) + s * bfhi(r));
}

static __device__ __forceinline__ void gload16(const void* g, void* s) {
    __builtin_amdgcn_global_load_lds(
        (const __attribute__((address_space(1))) uint32_t*)g,
        (__attribute__((address_space(3))) uint32_t*)s,
        16, 0, 0);
}

static __device__ __forceinline__ int detect_mode(const void* grid) {
    uint16_t g0 = ((const uint16_t*)grid)[0];   // grid[0][0] == 0.5 exactly
    if (g0 == 0x3800u) return MODE_F16;
    if (g0 == 0x3F00u) return MODE_BF16;
    return MODE_F32;
}

// ===========================================================================
// SPLIT PATH (f32 world, needs 64 MB d_ws)
// ===========================================================================

// Fused prologue: blocks [0,8192) convert A f32->bf16 (8 floats/thread,
// coalesced uint4 stores); blocks [8192,16384) decode one 3-byte code/thread
// -> 8 bf16 weights (16B coalesced store). Branch is block-uniform.
// One launch instead of two: overlaps both memory streams, saves a dispatch.
__global__ void prep_f32(const float* __restrict__ A,
                         const uint32_t* __restrict__ Q,
                         const float* __restrict__ grid,
                         const float* __restrict__ e81b,
                         uint16_t* __restrict__ Abf,
                         uint16_t* __restrict__ W)
{
    if (detect_mode(grid) != MODE_F32) return;
    const int b = blockIdx.x;
    const int t = threadIdx.x;

    if (b < 8192) {
        // ---- A conversion ----
        size_t idx = (size_t)b * 256 + t;                  // 2097152 threads
        const float4* src = (const float4*)A + idx * 2;
        float4 f0 = src[0], f1 = src[1];
        ((uint4*)Abf)[idx] = make_uint4(pk(f0.x, f0.y), pk(f0.z, f0.w),
                                        pk(f1.x, f1.y), pk(f1.z, f1.w));
    } else {
        // ---- W decode (byte-offset extraction validated round 3) ----
        __shared__ float e8f[2048];
        #pragma unroll
        for (int i = 0; i < 8; ++i) e8f[t + 256 * i] = e81b[t + 256 * i];
        __syncthreads();

        int ci  = (b - 8192) * 256 + t;                    // 2097152 codes
        size_t byt = (size_t)ci * 3;
        int dw = (int)(byt >> 2), off = (int)(byt & 3);
        uint32_t w0 = Q[dw];
        uint32_t w1 = (off > 1) ? Q[dw + 1] : 0u;
        uint32_t code = (uint32_t)(((((uint64_t)w1) << 32) | w0) >> (off * 8)) & 0xFFFFFFu;

        const float4* gr = (const float4*)(grid + (size_t)(code >> 8) * 8);
        const float*  rr = &e8f[(code & 255u) * 8];
        float4 g0 = gr[0], g1 = gr[1];
        const float S = 1.0f / 2.04f;
        ((uint4*)W)[ci] = make_uint4(
            pk(g0.x + S * rr[0], g0.y + S * rr[1]),
            pk(g0.z + S * rr[2], g0.w + S * rr[3]),
            pk(g1.x + S * rr[4], g1.y + S * rr[5]),
            pk(g1.z + S * rr[6], g1.w + S * rr[7]));
    }
}

// m97-structure bf16 BT-GEMM (PROVEN round 8: 137.9us, 996 TF, 0 bank
// conflicts): 128x128 tile, BK=64, 4 waves, 16x16x32 MFMA,
// global_load_lds(16B) both operands, linear LDS dest + inverse-XOR-swizzled
// source + swizzled ds_read (conflict-free b128). f32 epilogue. UNCHANGED.
__global__ void gemm_split(const uint16_t* __restrict__ A,
                           const uint16_t* __restrict__ B,
                           const float* __restrict__ grid,
                           float* __restrict__ C)
{
    if (detect_mode(grid) != MODE_F32) return;

    __shared__ uint16_t Alds[128 * 64];
    __shared__ uint16_t Blds[128 * 64];

    int t = threadIdx.x, l = t & 63, w = t >> 6;
    int bid = blockIdx.x;                      // 1024 wgs, bijective XCD swizzle
    int swz = (bid & 7) * 128 + (bid >> 3);
    int bm = swz >> 5, bn = swz & 31;
    size_t mbase = (size_t)bm * 128, nbase = (size_t)bn * 128;

    int lr8 = l >> 3, lc8 = l & 7, l15 = l & 15, lh = l >> 4;
    int wr = w >> 1, wc = w & 1;

    f32x4 acc[4][4] = {};

    for (int kt = 0; kt < K_IN / 64; ++kt) {
        __syncthreads();                       // prev iter's LDS reads done
        #pragma unroll
        for (int i = 0; i < 4; ++i) {
            int row = w * 32 + i * 8 + lr8;
            int cg  = lc8 ^ (row & 7);
            gload16(A + (mbase + row) * K_IN + kt * 64 + cg * 8,
                    &Alds[(w * 32 + i * 8) * 64]);
            gload16(B + (nbase + row) * K_IN + kt * 64 + cg * 8,
                    &Blds[(w * 32 + i * 8) * 64]);
        }
        __syncthreads();                       // vmcnt(0) drain: tiles ready

        #pragma unroll
        for (int ks = 0; ks < 2; ++ks) {
            bf16x8 af[4], bfr[4];
            #pragma unroll
            for (int i = 0; i < 4; ++i) {
                int ar = wr * 64 + i * 16 + l15;
                af[i] = *(const bf16x8*)&Alds[ar * 64 + (((ks << 2) | lh) ^ (ar & 7)) * 8];
            }
            #pragma unroll
            for (int j = 0; j < 4; ++j) {
                int br = wc * 64 + j * 16 + l15;
                bfr[j] = *(const bf16x8*)&Blds[br * 64 + (((ks << 2) | lh) ^ (br & 7)) * 8];
            }
            #pragma unroll
            for (int i = 0; i < 4; ++i)
                #pragma unroll
                for (int j = 0; j < 4; ++j)
                    acc[i][j] = __builtin_amdgcn_mfma_f32_16x16x32_bf16(
                        af[i], bfr[j], acc[i][j], 0, 0, 0);
        }
    }

    #pragma unroll
    for (int i = 0; i < 4; ++i)
        #pragma unroll
        for (int j = 0; j < 4; ++j) {
            size_t r0 = mbase + wr * 64 + i * 16 + lh * 4;
            size_t c0 = nbase + wc * 64 + j * 16 + l15;
            #pragma unroll
            for (int v = 0; v < 4; ++v)
                C[(r0 + v) * N_OUT + c0] = acc[i][j][v];
        }
}

// ===========================================================================
// FALLBACK PATHS (only launched when ws_size < 64 MB; validated round 4)
// ===========================================================================
template<int MODE>
__global__ void fused16(const uint16_t* __restrict__ A,
                        const uint32_t* __restrict__ Q,
                        const uint32_t* __restrict__ grid,
                        const uint32_t* __restrict__ e81b,
                        uint16_t* __restrict__ C)
{
    if (detect_mode(grid) != MODE) return;

    __shared__ uint16_t Alds[128 * 64];
    __shared__ uint16_t Blds[128 * 64];
    __shared__ uint4 e8[256];

    int t = threadIdx.x;
    int l = t & 63, w = t >> 6;
    e8[t] = ((const uint4*)e81b)[t];

    int bid = blockIdx.x;
    int swz = (bid & 7) * 128 + (bid >> 3);
    int bm = swz >> 5, bn = swz & 31;
    size_t mbase = (size_t)bm * 128, nbase = (size_t)bn * 128;

    int lr8 = l >> 3, lc8 = l & 7, l15 = l & 15, lh = l >> 4;
    int wr = w >> 1, wc = w & 1;

    int rB = t >> 1, hB = t & 1;
    const uint32_t* qrow = Q + (nbase + rB) * 384;
    uint16_t* blds_row = &Blds[rB * 64];
    int r7 = rB & 7;

    h2 s16;
    { union { uint32_t u; h2 h; } c; c.u = 0x37D837D8u; s16 = c.h; }
    const float sbf = 0.490234375f;

    f32x4 acc[4][4] = {};
    __syncthreads();

    for (int kt = 0; kt < K_IN / 64; ++kt) {
        #pragma unroll
        for (int i = 0; i < 4; ++i) {
            int arow = w * 32 + i * 8 + lr8;
            gload16(A + (mbase + arow) * K_IN + kt * 64 + (lc8 ^ (arow & 7)) * 8,
                    &Alds[(w * 32 + i * 8) * 64]);
        }
        {
            const uint32_t* src = qrow + kt * 6 + hB * 3;
            uint32_t w0 = src[0], w1 = src[1], w2 = src[2];
            uint32_t code[4] = {
                w0 & 0xFFFFFFu,
                (w0 >> 24) | ((w1 & 0xFFFFu) << 8),
                (w1 >> 16) | ((w2 & 0xFFu) << 16),
                w2 >> 8
            };
            #pragma unroll
            for (int j = 0; j < 4; ++j) {
                uint4 g = ((const uint4*)grid)[code[j] >> 8];
                uint4 r = e8[code[j] & 255];
                uint32_t o[4];
                if constexpr (MODE == MODE_F16) {
                    o[0] = fma_h2(g.x, r.x, s16); o[1] = fma_h2(g.y, r.y, s16);
                    o[2] = fma_h2(g.z, r.z, s16); o[3] = fma_h2(g.w, r.w, s16);
                } else {
                    o[0] = fma_b2(g.x, r.x, sbf); o[1] = fma_b2(g.y, r.y, sbf);
                    o[2] = fma_b2(g.z, r.z, sbf); o[3] = fma_b2(g.w, r.w, sbf);
                }
                int cglob = hB * 4 + j;
                *(uint4*)&blds_row[(cglob ^ r7) * 8] = make_uint4(o[0], o[1], o[2], o[3]);
            }
        }
        __syncthreads();

        #pragma unroll
        for (int ks = 0; ks < 2; ++ks) {
            #pragma unroll
            for (int i = 0; i < 4; ++i) {
                int ar = wr * 64 + i * 16 + l15;
                const uint16_t* ap = &Alds[ar * 64 + (((ks << 2) | lh) ^ (ar & 7)) * 8];
                #pragma unroll
                for (int j = 0; j < 4; ++j) {
                    int br = wc * 64 + j * 16 + l15;
                    const uint16_t* bp = &Blds[br * 64 + (((ks << 2) | lh) ^ (br & 7)) * 8];
                    if constexpr (MODE == MODE_F16)
                        acc[i][j] = __builtin_amdgcn_mfma_f32_16x16x32_f16(
                            *(const f16x8*)ap, *(const f16x8*)bp, acc[i][j], 0, 0, 0);
                    else
                        acc[i][j] = __builtin_amdgcn_mfma_f32_16x16x32_bf16(
                            *(const bf16x8*)ap, *(const bf16x8*)bp, acc[i][j], 0, 0, 0);
                }
            }
        }
        __syncthreads();
    }

    #pragma unroll
    for (int i = 0; i < 4; ++i)
        #pragma unroll
        for (int j = 0; j < 4; ++j) {
            size_t r0 = mbase + wr * 64 + i * 16 + lh * 4;
            size_t c0 = nbase + wc * 64 + j * 16 + l15;
            #pragma unroll
            for (int v = 0; v < 4; ++v) {
                float x = acc[i][j][v];
                C[(r0 + v) * N_OUT + c0] = (MODE == MODE_F16) ? f2h(x) : f2b(x);
            }
        }
}

__global__ void fused32(const float* __restrict__ A,
                        const uint32_t* __restrict__ Q,
                        const float* __restrict__ grid,
                        const float* __restrict__ e81b,
                        float* __restrict__ C)
{
    if (detect_mode(grid) != MODE_F32) return;

    __shared__ uint16_t Alds[128 * 64];
    __shared__ uint16_t Blds[128 * 64];
    __shared__ float e8f[256 * 8];

    int t = threadIdx.x;
    int l = t & 63, w = t >> 6;
    #pragma unroll
    for (int i = 0; i < 8; ++i) e8f[t * 8 + i] = e81b[t * 8 + i];

    int bid = blockIdx.x;
    int swz = (bid & 7) * 128 + (bid >> 3);
    int bm = swz >> 5, bn = swz & 31;
    size_t mbase = (size_t)bm * 128, nbase = (size_t)bn * 128;

    int lr8 = l >> 3, lc8 = l & 7, l15 = l & 15, lh = l >> 4;
    int wr = w >> 1, wc = w & 1;

    int rB = t >> 1, hB = t & 1;
    const uint32_t* qrow = Q + (nbase + rB) * 384;
    uint16_t* blds_row = &Blds[rB * 64];
    int r7 = rB & 7;
    const float S = 1.0f / 2.04f;

    f32x4 acc[4][4] = {};
    __syncthreads();

    for (int kt = 0; kt < K_IN / 64; ++kt) {
        #pragma unroll
        for (int i = 0; i < 4; ++i) {
            int arow = w * 32 + i * 8 + lr8;
            const float* src = A + (mbase + arow) * (size_t)K_IN + kt * 64 + lc8 * 8;
            float4 f0 = ((const float4*)src)[0];
            float4 f1 = ((const float4*)src)[1];
            uint4 o = make_uint4(pk(f0.x, f0.y), pk(f0.z, f0.w),
                                 pk(f1.x, f1.y), pk(f1.z, f1.w));
            *(uint4*)&Alds[arow * 64 + (lc8 ^ (arow & 7)) * 8] = o;
        }
        {
            const uint32_t* src = qrow + kt * 6 + hB * 3;
            uint32_t w0 = src[0], w1 = src[1], w2 = src[2];
            uint32_t code[4] = {
                w0 & 0xFFFFFFu,
                (w0 >> 24) | ((w1 & 0xFFFFu) << 8),
                (w1 >> 16) | ((w2 & 0xFFu) << 16),
                w2 >> 8
            };
            #pragma unroll
            for (int j = 0; j < 4; ++j) {
                const float* gr = grid + (size_t)(code[j] >> 8) * 8;
                const float* rr = &e8f[(code[j] & 255u) * 8];
                float4 g0 = ((const float4*)gr)[0];
                float4 g1 = ((const float4*)gr)[1];
                uint4 o = make_uint4(
                    pk(g0.x + S * rr[0], g0.y + S * rr[1]),
                    pk(g0.z + S * rr[2], g0.w + S * rr[3]),
                    pk(g1.x + S * rr[4], g1.y + S * rr[5]),
                    pk(g1.z + S * rr[6], g1.w + S * rr[7]));
                int cglob = hB * 4 + j;
                *(uint4*)&blds_row[(cglob ^ r7) * 8] = o;
            }
        }
        __syncthreads();

        #pragma unroll
        for (int ks = 0; ks < 2; ++ks) {
            #pragma unroll
            for (int i = 0; i < 4; ++i) {
                int ar = wr * 64 + i * 16 + l15;
                const uint16_t* ap = &Alds[ar * 64 + (((ks << 2) | lh) ^ (ar & 7)) * 8];
                #pragma unroll
                for (int j = 0; j < 4; ++j) {
                    int br = wc * 64 + j * 16 + l15;
                    const uint16_t* bp = &Blds[br * 64 + (((ks << 2) | lh) ^ (br & 7)) * 8];
                    acc[i][j] = __builtin_amdgcn_mfma_f32_16x16x32_bf16(
                        *(const bf16x8*)ap, *(const bf16x8*)bp, acc[i][j], 0, 0, 0);
                }
            }
        }
        __syncthreads();
    }

    #pragma unroll
    for (int i = 0; i < 4; ++i)
        #pragma unroll
        for (int j = 0; j < 4; ++j) {
            size_t r0 = mbase + wr * 64 + i * 16 + lh * 4;
            size_t c0 = nbase + wc * 64 + j * 16 + l15;
            #pragma unroll
            for (int v = 0; v < 4; ++v)
                C[(r0 + v) * N_OUT + c0] = acc[i][j][v];
        }
}

extern "C" void kernel_launch(void* const* d_in, const int* in_sizes, int n_in,
                              void* d_out, int out_size, void* d_ws, size_t ws_size,
                              hipStream_t stream) {
    const void*     A    = d_in[0];
    const uint32_t* Q    = (const uint32_t*)d_in[1];
    const void*     grid = d_in[2];
    const void*     e81b = d_in[3];
    for (int i = 0; i < n_in; ++i) {
        if (in_sizes[i] == 16777216)      A    = d_in[i];
        else if (in_sizes[i] == 1572864)  Q    = (const uint32_t*)d_in[i];
        else if (in_sizes[i] == 524288)   grid = d_in[i];
        else if (in_sizes[i] == 2048)     e81b = d_in[i];
    }

    const bool split = ws_size >= (size_t)(64u << 20);   // 32 MB W + 32 MB A(bf16)

    if (split) {
        // f32 world confirmed on-device (rounds 3/4/8: detect_mode==F32 every
        // run); prep_f32/gemm_split self-gate on it regardless.
        uint16_t* Wbf = (uint16_t*)d_ws;                  // [4096][4096] bf16
        uint16_t* Abf = (uint16_t*)d_ws + 16777216;       // [4096][4096] bf16
        prep_f32  <<<16384, 256, 0, stream>>>((const float*)A, Q, (const float*)grid,
                                              (const float*)e81b, Abf, Wbf);
        gemm_split<<<1024, 256, 0, stream>>>(Abf, Wbf, (const float*)grid, (float*)d_out);
    } else {
        fused16<MODE_F16><<<1024, 256, 0, stream>>>(
            (const uint16_t*)A, Q, (const uint32_t*)grid, (const uint32_t*)e81b,
            (uint16_t*)d_out);
        fused16<MODE_BF16><<<1024, 256, 0, stream>>>(
            (const uint16_t*)A, Q, (const uint32_t*)grid, (const uint32_t*)e81b,
            (uint16_t*)d_out);
        fused32<<<1024, 256, 0, stream>>>(
            (const float*)A, Q, (const float*)grid, (const float*)e81b,
            (float*)d_out);
    }
}